// Round 12
// baseline (558.004 us; speedup 1.0000x reference)
//
#include <hip/hip_runtime.h>
#include <hip/hip_bf16.h>

#define N_NODES   100000
#define N_HALF    50000
#define N_EDGES   3200000
#define F_IN      100
#define H_DIM     64
#define C_NUM     18
#define NPB       128                       // nodes per csr bucket
#define N_BKT     782                       // ceil(100000/128)
#define EPB_C     8192                      // edges per radix-count block
#define EPB_S     4096                      // edges per radix-scatter block
#define N_TILES   1563                      // ceil(100000/64)

typedef __attribute__((ext_vector_type(8))) short short8;
typedef __attribute__((ext_vector_type(4))) float f32x4;
typedef __attribute__((ext_vector_type(2))) float f32x2;

// ---- dtype-flexible loads (flags decided at runtime by detect_kernel) ----
__device__ __forceinline__ float ldf(const void* p, long long i, int isbf) {
    if (isbf) return __bfloat162float(((const __hip_bfloat16*)p)[i]);
    return ((const float*)p)[i];
}
// node indices are < 2^17, so for int64 input the LOW DWORD suffices
// (little-endian): halves edge-index traffic vs 8B loads.
__device__ __forceinline__ int ldi_lo(const void* p, long long i, int is64) {
    if (is64) return ((const int*)p)[2 * i];
    return ((const int*)p)[i];
}
__device__ __forceinline__ unsigned short f2us(float f) {
    __hip_bfloat16 b = __float2bfloat16(f);
    return *(unsigned short*)&b;
}
__device__ __forceinline__ unsigned char f2fp8(float f) {
    int p = __builtin_amdgcn_cvt_pk_fp8_f32(f, 0.0f, 0, false);
    return (unsigned char)(p & 0xFF);
}

// ---- probe input dtypes; write flags; zero pcnt (merged zero_cnt) ----
__global__ void detect_kernel(const void* ei, const void* x, int* flags,
                              int* __restrict__ pcnt)
{
    const int t = threadIdx.x;
    for (int i = t; i < N_BKT; i += 256) pcnt[i] = 0;
    if (t >= 64) return;
    const int lane = t;
    const long long* e64 = (const long long*)ei;
    int bad = 0;
#pragma unroll
    for (int i = lane; i < 128; i += 64) {
        long long v = e64[i];
        if (v < 0 || v >= N_NODES) bad = 1;
    }
    unsigned long long anybad = __ballot(bad);
    const __hip_bfloat16* xb = (const __hip_bfloat16*)x;
    int cnt = 0;
#pragma unroll
    for (int i = lane; i < 256; i += 64) {
        float v = fabsf(__bfloat162float(xb[i]));
        if (v == 0.0f || (v > 9.5367431640625e-7f && v < 1.0e6f)) ++cnt;
    }
#pragma unroll
    for (int m = 1; m <= 32; m <<= 1) cnt += __shfl_xor(cnt, m);
    if (lane == 0) {
        flags[0] = (anybad == 0ULL) ? 1 : 0;
        flags[1] = (cnt >= 240) ? 1 : 0;
    }
}

// ---- pass A: bucket histogram, LDS-privatized (bucket = dst>>7) ----
__global__ __launch_bounds__(1024) void radix_count(const void* ei, int* __restrict__ pcnt,
                                                    const int* __restrict__ flags)
{
    __shared__ int hist[N_BKT];
    const int t = threadIdx.x;
    if (t < N_BKT) hist[t] = 0;
    __syncthreads();
    const int base = blockIdx.x * EPB_C;
    const int n = min(EPB_C, N_EDGES - base);
    const int is64 = flags[0];
    for (int j = t; j < n; j += 1024) {
        int d = ldi_lo(ei, (long long)N_EDGES + base + j, is64);
        atomicAdd(&hist[d >> 7], 1);
    }
    __syncthreads();
    if (t < N_BKT) atomicAdd(&pcnt[t], hist[t]);
}

// ---- prefix scan over 782 bucket counts (single block of 1024) ----
__global__ __launch_bounds__(1024) void scan_bkt(const int* __restrict__ cnt,
                                                 int* __restrict__ base,
                                                 int* __restrict__ cursor)
{
    __shared__ int tmp[1024];
    const int t = threadIdx.x;
    int v = (t < N_BKT) ? cnt[t] : 0;
    tmp[t] = v;
    __syncthreads();
    for (int off = 1; off < 1024; off <<= 1) {
        int add = (t >= off) ? tmp[t - off] : 0;
        __syncthreads();
        tmp[t] += add;
        __syncthreads();
    }
    if (t < N_BKT) { base[t] = tmp[t] - v; cursor[t] = tmp[t] - v; }
    if (t == 1023) base[N_BKT] = tmp[1023];   // == N_EDGES
}

// ---- pass B: LDS-staged radix partition into contiguous bucket regions ----
// stage[].x: src:17b | local-node(7b)<<17 ; stage[].y: w16 | bucket<<16
__global__ __launch_bounds__(1024) void radix_scatter(const void* ei, const void* ew,
                                                      int* __restrict__ gcursor,
                                                      uint2* __restrict__ temp,
                                                      const int* __restrict__ flags)
{
    __shared__ uint2 stage[EPB_S];                // 32 KB
    __shared__ int hist[1024], scan_s[1024];      // 8 KB
    __shared__ int gbase[N_BKT], lcur[N_BKT];     // ~6.3 KB
    const int t = threadIdx.x;
    hist[t] = 0;
    __syncthreads();

    const int base = blockIdx.x * EPB_S;
    const int n = min(EPB_S, N_EDGES - base);
    const int is64 = flags[0], isbf = flags[1];

    int  bkt[4];
    uint2 pk[4];
#pragma unroll
    for (int j = 0; j < 4; ++j) {
        int i = j * 1024 + t;
        bkt[j] = -1;
        if (i < n) {
            int e = base + i;
            int s = ldi_lo(ei, e, is64);
            int d = ldi_lo(ei, (long long)N_EDGES + e, is64);
            float w = ldf(ew, e, isbf);
            bkt[j] = d >> 7;
            pk[j].x = (unsigned)s | ((unsigned)(d & (NPB - 1)) << 17);
            pk[j].y = (unsigned)f2us(w) | ((unsigned)bkt[j] << 16);
            atomicAdd(&hist[bkt[j]], 1);
        }
    }
    __syncthreads();
    scan_s[t] = hist[t];
    __syncthreads();
    for (int off = 1; off < 1024; off <<= 1) {
        int add = (t >= off) ? scan_s[t - off] : 0;
        __syncthreads();
        scan_s[t] += add;
        __syncthreads();
    }
    if (t < N_BKT) {
        int excl = scan_s[t] - hist[t];
        lcur[t] = excl;
        gbase[t] = atomicAdd(&gcursor[t], hist[t]) - excl;
    }
    __syncthreads();
#pragma unroll
    for (int j = 0; j < 4; ++j) {
        if (bkt[j] >= 0) {
            int pos = atomicAdd(&lcur[bkt[j]], 1);
            stage[pos] = pk[j];
        }
    }
    __syncthreads();
#pragma unroll
    for (int j = 0; j < 4; ++j) {
        int i = j * 1024 + t;
        if (i < n) {
            int b = (int)(stage[i].y >> 16);
            temp[gbase[b] + i] = stage[i];
        }
    }
}

// ---- pass C: per-bucket CSR finalize (128 nodes/block, 782 blocks) ----
// csr entry: src:17b | bf16-weight-without-sign:15b (weights >= 0)
__global__ __launch_bounds__(NPB) void csr_build(const uint2* __restrict__ temp,
                          const int* __restrict__ pbase,
                          unsigned int* __restrict__ csr_pk,
                          int* __restrict__ deg, int* __restrict__ row_start,
                          float* __restrict__ inv_deg)
{
    __shared__ int cnt[NPB], scan_s[NPB], cur[NPB];
    const int b = blockIdx.x;
    const int t = threadIdx.x;
    cnt[t] = 0;
    __syncthreads();
    const int bs = pbase[b];
    const int be = pbase[b + 1];
    for (int i = bs + t; i < be; i += NPB)
        atomicAdd(&cnt[(temp[i].x >> 17) & (NPB - 1)], 1);
    __syncthreads();
    int v = cnt[t];
    scan_s[t] = v;
    __syncthreads();
    for (int off = 1; off < NPB; off <<= 1) {
        int add = (t >= off) ? scan_s[t - off] : 0;
        __syncthreads();
        scan_s[t] += add;
        __syncthreads();
    }
    int excl = bs + scan_s[t] - v;
    cur[t] = excl;
    int node = b * NPB + t;
    if (node < N_NODES) {
        deg[node]       = v;
        row_start[node] = excl;
        inv_deg[node]   = 1.0f / (float)max(v, 1);
    }
    __syncthreads();
    for (int i = bs + t; i < be; i += NPB) {
        uint2 e = temp[i];
        int k = (e.x >> 17) & (NPB - 1);
        int pos = atomicAdd(&cur[k], 1);
        csr_pk[pos] = (e.x & 0x1FFFFu) | ((e.y & 0x7FFFu) << 17);
    }
}

// conflict-free W staging into W_s[n*KP + k] (KP=136): lane group n=t>>3, k8=t&7
template <int CP, int COUT>
__device__ __forceinline__ void stage_W(unsigned short* W_s, const void* Wl, const void* Wr,
                                        int t, int isbf)
{
    constexpr int KP = 136;
    const int n0 = t >> 3, k8a = t & 7;
    for (int n = n0; n < CP; n += 32) {
#pragma unroll
        for (int hh = 0; hh < 2; ++hh) {
            int k8 = k8a + hh * 8;
            union { unsigned short u[8]; short8 v; } tmp;
#pragma unroll
            for (int j = 0; j < 8; ++j) {
                int k = k8 * 8 + j;
                float val = 0.0f;
                if (n < COUT && k < 128)
                    val = (k < 64) ? ldf(Wl, (long long)k * COUT + n, isbf)
                                   : ldf(Wr, (long long)(k - 64) * COUT + n, isbf);
                tmp.u[j] = f2us(val);
            }
            *(short8*)&W_s[n * KP + k8 * 8] = tmp.v;
        }
    }
}

// ---- embedding via MFMA: h = relu(x @ W + b); also writes flat fp8 copy h8 ----
__global__ void embed_mfma(const void* x, const void* W, const void* b,
                           __hip_bfloat16* __restrict__ h,
                           unsigned char* __restrict__ h8,
                           const int* __restrict__ flags)
{
    constexpr int KP = 136;
    __shared__ unsigned short W_s[H_DIM * KP];
    __shared__ unsigned short x_s[64 * KP];
    __shared__ float b_s[H_DIM];
    const int t = threadIdx.x;
    const int isbf = flags[1];

    {
        const int n0 = t >> 3, k8a = t & 7;
        for (int n = n0; n < H_DIM; n += 32) {
#pragma unroll
            for (int hh = 0; hh < 2; ++hh) {
                int k8 = k8a + hh * 8;
                union { unsigned short u[8]; short8 v; } tmp;
#pragma unroll
                for (int j = 0; j < 8; ++j) {
                    int k = k8 * 8 + j;
                    tmp.u[j] = (k < F_IN) ? f2us(ldf(W, (long long)k * H_DIM + n, isbf))
                                          : (unsigned short)0;
                }
                *(short8*)&W_s[n * KP + k8 * 8] = tmp.v;
            }
        }
    }
    if (t < H_DIM) b_s[t] = ldf(b, t, isbf);
    for (int i = t; i < 64 * 36; i += 256) {
        int row = i / 36, col = 100 + (i % 36);
        x_s[row * KP + col] = 0;
    }

    const int wave = t >> 6, lane = t & 63, c = lane & 15, quad = lane >> 4;

    for (int tile = blockIdx.x; tile < N_TILES; tile += gridDim.x) {
        const int nb0 = tile * 64;
        const int valid = min(64, N_NODES - nb0);
        __syncthreads();   // prior tile's reads done
        if (isbf) {
            const uint2* xu = (const uint2*)x + (size_t)nb0 * 25;   // 25 uint2 per row
            for (int i2 = t; i2 < valid * 25; i2 += 256) {
                int row = i2 / 25, col4 = i2 - row * 25;
                *(uint2*)&x_s[row * KP + col4 * 4] = xu[i2];
            }
        } else {
            for (int i = t; i < valid * 100; i += 256) {
                int row = i / 100, col = i - row * 100;
                x_s[row * KP + col] = f2us(((const float*)x)[(size_t)(nb0 + row) * 100 + col]);
            }
        }
        if (valid < 64) {
            for (int i = t; i < (64 - valid) * 100; i += 256) {
                int row = valid + i / 100, col = i % 100;
                x_s[row * KP + col] = 0;
            }
        }
        __syncthreads();

        short8 bfrag[4][4];
#pragma unroll
        for (int nt = 0; nt < 4; ++nt)
#pragma unroll
            for (int kt = 0; kt < 4; ++kt)
                bfrag[nt][kt] = *(const short8*)&W_s[(nt * 16 + c) * KP + kt * 32 + quad * 8];

        short8 afrag[4];
#pragma unroll
        for (int kt = 0; kt < 4; ++kt)
            afrag[kt] = *(const short8*)&x_s[(wave * 16 + c) * KP + kt * 32 + quad * 8];

        f32x4 acc[4] = {};
#pragma unroll
        for (int nt = 0; nt < 4; ++nt)
#pragma unroll
            for (int kt = 0; kt < 4; ++kt)
                acc[nt] = __builtin_amdgcn_mfma_f32_16x16x32_bf16(afrag[kt], bfrag[nt][kt], acc[nt], 0, 0, 0);

        const int nb = nb0 + wave * 16;
#pragma unroll
        for (int nt = 0; nt < 4; ++nt)
#pragma unroll
            for (int reg = 0; reg < 4; ++reg) {
                int nn = nb + quad * 4 + reg;
                int col = nt * 16 + c;
                if (nn < N_NODES) {
                    float v = fmaxf(acc[nt][reg] + b_s[col], 0.0f);
                    h[(size_t)nn * H_DIM + col] = __float2bfloat16(v);
                    h8[(size_t)nn * H_DIM + col] = f2fp8(v);
                }
            }
    }
}

// ---- gather: mean[n] = inv_deg * sum_j w_j * h8[src_j]; ONE node per wave ----
// Measured-best structure (r8, 51us). MEASUREMENT ROUND: node range [nlo,nhi)
// is a parameter; each layer's gather is split into two ~25us half dispatches
// so second-tier kernels (transform/prep) can surface in the top-5 table.
#define ACC16(HV, W) do {                                                          \
    f32x2 f_;                                                                      \
    f_ = __builtin_amdgcn_cvt_pk_f32_fp8((int)HV.x, false); a[0]=fmaf(W,f_.x,a[0]);  a[1]=fmaf(W,f_.y,a[1]);   \
    f_ = __builtin_amdgcn_cvt_pk_f32_fp8((int)HV.x, true ); a[2]=fmaf(W,f_.x,a[2]);  a[3]=fmaf(W,f_.y,a[3]);   \
    f_ = __builtin_amdgcn_cvt_pk_f32_fp8((int)HV.y, false); a[4]=fmaf(W,f_.x,a[4]);  a[5]=fmaf(W,f_.y,a[5]);   \
    f_ = __builtin_amdgcn_cvt_pk_f32_fp8((int)HV.y, true ); a[6]=fmaf(W,f_.x,a[6]);  a[7]=fmaf(W,f_.y,a[7]);   \
    f_ = __builtin_amdgcn_cvt_pk_f32_fp8((int)HV.z, false); a[8]=fmaf(W,f_.x,a[8]);  a[9]=fmaf(W,f_.y,a[9]);   \
    f_ = __builtin_amdgcn_cvt_pk_f32_fp8((int)HV.z, true ); a[10]=fmaf(W,f_.x,a[10]); a[11]=fmaf(W,f_.y,a[11]); \
    f_ = __builtin_amdgcn_cvt_pk_f32_fp8((int)HV.w, false); a[12]=fmaf(W,f_.x,a[12]); a[13]=fmaf(W,f_.y,a[13]); \
    f_ = __builtin_amdgcn_cvt_pk_f32_fp8((int)HV.w, true ); a[14]=fmaf(W,f_.x,a[14]); a[15]=fmaf(W,f_.y,a[15]); \
} while (0)

template <bool USE_W>
__global__ __launch_bounds__(256) void gather_mean(const unsigned char* __restrict__ h8,
                            const unsigned int* __restrict__ csr_pk,
                            const int* __restrict__ row_start,
                            const int* __restrict__ deg,
                            const float* __restrict__ inv_deg,
                            __hip_bfloat16* __restrict__ mean,
                            int nlo, int nhi)
{
    const int lane = threadIdx.x & 63;
    const int c4 = lane & 3;
    const int r4 = lane >> 2;               // 0..15
    const int wid = blockIdx.x * 4 + (threadIdx.x >> 6);
    const int nw  = gridDim.x * 4;

    for (int n = nlo + wid; n < nhi; n += nw) {
        const int s0 = row_start[n];
        const int d0 = deg[n];
        unsigned int ev = (lane < d0) ? csr_pk[s0 + lane] : 0u;
        const int m0 = min(d0, 64);
        float a[16] = {};

        for (int j0 = 0; j0 < m0; j0 += 32) {   // wave-uniform: 1 or 2 iters
            unsigned int eA = __shfl(ev, j0 + r4);
            unsigned int eB = __shfl(ev, j0 + 16 + r4);
            uint4 hvA = *(const uint4*)(h8 + (size_t)(eA & 0x1FFFF) * H_DIM + 16 * c4);
            uint4 hvB = *(const uint4*)(h8 + (size_t)(eB & 0x1FFFF) * H_DIM + 16 * c4);
            float wA, wB;
            if (USE_W) {
                wA = __uint_as_float((eA & 0xFFFE0000u) >> 1);   // e=0 -> w=0
                wB = __uint_as_float((eB & 0xFFFE0000u) >> 1);
            } else {
                wA = (j0 + r4 < m0) ? 1.0f : 0.0f;
                wB = (j0 + 16 + r4 < m0) ? 1.0f : 0.0f;
            }
            ACC16(hvA, wA);
            ACC16(hvB, wB);
        }
        // rare tail (deg > 64)
        for (int jb = 64; jb < d0; jb += 16) {
            int j = jb + r4;
            unsigned int e2 = (j < d0) ? csr_pk[s0 + j] : 0u;
            float w;
            if (USE_W) w = __uint_as_float((e2 & 0xFFFE0000u) >> 1);
            else       w = (j < d0) ? 1.0f : 0.0f;
            uint4 hv = *(const uint4*)(h8 + (size_t)(e2 & 0x1FFFF) * H_DIM + 16 * c4);
            ACC16(hv, w);
        }

        // split-butterfly reduce over the 16 r4-groups (masks 4,8,16,32)
#pragma unroll
        for (int i = 0; i < 8; ++i) {
            float keep = (lane & 4) ? a[i + 8] : a[i];
            float give = (lane & 4) ? a[i] : a[i + 8];
            a[i] = keep + __shfl_xor(give, 4);
        }
#pragma unroll
        for (int i = 0; i < 4; ++i) {
            float keep = (lane & 8) ? a[i + 4] : a[i];
            float give = (lane & 8) ? a[i] : a[i + 4];
            a[i] = keep + __shfl_xor(give, 8);
        }
#pragma unroll
        for (int i = 0; i < 2; ++i) {
            float keep = (lane & 16) ? a[i + 2] : a[i];
            float give = (lane & 16) ? a[i] : a[i + 2];
            a[i] = keep + __shfl_xor(give, 16);
        }
        {
            float keep = (lane & 32) ? a[1] : a[0];
            float give = (lane & 32) ? a[0] : a[1];
            a[0] = keep + __shfl_xor(give, 32);
        }
        // lane's owned feature after the 4 keep-half decisions:
        const int f = c4 * 16 + ((lane >> 2) & 1) * 8 + ((lane >> 3) & 1) * 4
                    + ((lane >> 4) & 1) * 2 + ((lane >> 5) & 1);
        mean[(size_t)n * H_DIM + f] = __float2bfloat16(a[0] * inv_deg[n]);
    }
}

// ---- transform via MFMA: out = L2norm([mean|h] @ [Wl;Wr] + b) ----
// Non-final layers also write the flat fp8 copy for the next gather.
template <int COUT, bool RELU, bool FINAL>
__global__ void transform_mfma(const __hip_bfloat16* __restrict__ meanp,
                               const __hip_bfloat16* __restrict__ hp,
                               const void* Wl, const void* bl, const void* Wr,
                               __hip_bfloat16* __restrict__ h_out,
                               unsigned char* __restrict__ h8_out,
                               const int* __restrict__ flags, void* dout)
{
    constexpr int CP = (COUT + 15) & ~15;   // 64 or 32
    constexpr int NT = CP / 16;
    constexpr int KP = 136;
    __shared__ unsigned short W_s[CP * KP];
    __shared__ float b_s[CP];
    const int t = threadIdx.x;
    const int isbf = flags[1];
    stage_W<CP, COUT>(W_s, Wl, Wr, t, isbf);
    if (t < CP) b_s[t] = (t < COUT) ? ldf(bl, t, isbf) : 0.0f;
    __syncthreads();

    const int wave = t >> 6, lane = t & 63, c = lane & 15, quad = lane >> 4;
    short8 bfrag[NT][4];
#pragma unroll
    for (int nt = 0; nt < NT; ++nt)
#pragma unroll
        for (int kt = 0; kt < 4; ++kt)
            bfrag[nt][kt] = *(const short8*)&W_s[(nt * 16 + c) * KP + kt * 32 + quad * 8];

    for (int tile = blockIdx.x; tile < N_TILES; tile += gridDim.x) {
        const int nbw = tile * 64 + wave * 16;
        if (nbw >= N_NODES) continue;
        int node = nbw + c; if (node >= N_NODES) node = N_NODES - 1;

        short8 afrag[4];
#pragma unroll
        for (int kt = 0; kt < 4; ++kt) {
            const __hip_bfloat16* sp = (kt < 2) ? meanp : hp;
            afrag[kt] = *(const short8*)(sp + (size_t)node * H_DIM + (kt & 1) * 32 + quad * 8);
        }

        f32x4 acc[NT] = {};
#pragma unroll
        for (int nt = 0; nt < NT; ++nt)
#pragma unroll
            for (int kt = 0; kt < 4; ++kt)
                acc[nt] = __builtin_amdgcn_mfma_f32_16x16x32_bf16(afrag[kt], bfrag[nt][kt], acc[nt], 0, 0, 0);

        float rs[4];
#pragma unroll
        for (int reg = 0; reg < 4; ++reg) {
            float s2 = 0.f;
#pragma unroll
            for (int nt = 0; nt < NT; ++nt) {
                float v = acc[nt][reg] + b_s[nt * 16 + c];
                acc[nt][reg] = v;
                s2 += v * v;
            }
            s2 += __shfl_xor(s2, 1); s2 += __shfl_xor(s2, 2);
            s2 += __shfl_xor(s2, 4); s2 += __shfl_xor(s2, 8);
            rs[reg] = 1.0f / fmaxf(sqrtf(s2), 1e-12f);
        }

#pragma unroll
        for (int nt = 0; nt < NT; ++nt)
#pragma unroll
            for (int reg = 0; reg < 4; ++reg) {
                int nn  = nbw + quad * 4 + reg;
                int col = nt * 16 + c;
                if (nn < N_NODES && col < COUT) {
                    float v = acc[nt][reg] * rs[reg];
                    if (RELU) v = fmaxf(v, 0.0f);
                    if (FINAL) {
                        if (isbf) ((__hip_bfloat16*)dout)[(size_t)nn * COUT + col] = __float2bfloat16(v);
                        else      ((float*)dout)[(size_t)nn * COUT + col] = v;
                    } else {
                        h_out[(size_t)nn * H_DIM + col] = __float2bfloat16(v);
                        h8_out[(size_t)nn * H_DIM + col] = f2fp8(v);
                    }
                }
            }
    }
}

extern "C" void kernel_launch(void* const* d_in, const int* in_sizes, int n_in,
                              void* d_out, int out_size, void* d_ws, size_t ws_size,
                              hipStream_t stream)
{
    const void* x    = d_in[0];
    const void* ei   = d_in[1];
    const void* ew   = d_in[2];
    const void* embW = d_in[3];
    const void* embB = d_in[4];
    const void* Wl1 = d_in[5];  const void* bl1 = d_in[6];  const void* Wr1 = d_in[7];
    const void* Wl2 = d_in[8];  const void* bl2 = d_in[9];  const void* Wr2 = d_in[10];
    const void* Wl3 = d_in[11]; const void* bl3 = d_in[12]; const void* Wr3 = d_in[13];
    const void* Wl4 = d_in[14]; const void* bl4 = d_in[15]; const void* Wr4 = d_in[16];
    (void)in_sizes; (void)n_in; (void)out_size; (void)ws_size;

    char* ws = (char*)d_ws;
    size_t off = 0;
    auto alloc = [&](size_t bytes) -> void* {
        void* p = ws + off;
        off += (bytes + 255) & ~(size_t)255;
        return p;
    };
    // temp (edge staging, 25.6 MB) is dead after csr_build; hA/hB alias it.
    uint2* temp = (uint2*)alloc((size_t)N_EDGES * sizeof(uint2));
    __hip_bfloat16* hA = (__hip_bfloat16*)temp;
    __hip_bfloat16* hB = (__hip_bfloat16*)((char*)temp + (size_t)N_NODES * H_DIM * 2);
    unsigned int* csr_pk = (unsigned int*)alloc((size_t)N_EDGES * sizeof(unsigned int));
    __hip_bfloat16* mn = (__hip_bfloat16*)alloc((size_t)N_NODES * H_DIM * 2);  // 12.8 MB
    unsigned char* h8A = (unsigned char*)alloc((size_t)N_NODES * H_DIM);   // 6.4 MB
    unsigned char* h8B = (unsigned char*)alloc((size_t)N_NODES * H_DIM);   // 6.4 MB
    int*   pcnt    = (int*)  alloc((N_BKT)     * sizeof(int));
    int*   pbase   = (int*)  alloc((N_BKT + 1) * sizeof(int));
    int*   pcursor = (int*)  alloc((N_BKT)     * sizeof(int));
    int*   deg     = (int*)  alloc((size_t)N_NODES * sizeof(int));
    int*   row_st  = (int*)  alloc((size_t)N_NODES * sizeof(int));
    float* inv_deg = (float*)alloc((size_t)N_NODES * sizeof(float));
    int*   flags   = (int*)  alloc(256);

    const int NBc = (N_EDGES + EPB_C - 1) / EPB_C;   // 391 count blocks
    const int NBs = (N_EDGES + EPB_S - 1) / EPB_S;   // 782 scatter blocks

    detect_kernel<<<1, 256, 0, stream>>>(ei, x, flags, pcnt);
    radix_count<<<NBc, 1024, 0, stream>>>(ei, pcnt, flags);
    scan_bkt<<<1, 1024, 0, stream>>>(pcnt, pbase, pcursor);
    radix_scatter<<<NBs, 1024, 0, stream>>>(ei, ew, pcursor, temp, flags);
    csr_build<<<N_BKT, NPB, 0, stream>>>(temp, pbase, csr_pk, deg, row_st, inv_deg);

    embed_mfma<<<512, 256, 0, stream>>>(x, embW, embB, hA, h8A, flags);

    gather_mean<true><<<2048, 256, 0, stream>>>(h8A, csr_pk, row_st, deg, inv_deg, mn, 0, N_HALF);
    gather_mean<true><<<2048, 256, 0, stream>>>(h8A, csr_pk, row_st, deg, inv_deg, mn, N_HALF, N_NODES);
    transform_mfma<H_DIM, true, false><<<N_TILES, 256, 0, stream>>>(
        mn, hA, Wl1, bl1, Wr1, hB, h8B, flags, d_out);
    gather_mean<true><<<2048, 256, 0, stream>>>(h8B, csr_pk, row_st, deg, inv_deg, mn, 0, N_HALF);
    gather_mean<true><<<2048, 256, 0, stream>>>(h8B, csr_pk, row_st, deg, inv_deg, mn, N_HALF, N_NODES);
    transform_mfma<H_DIM, true, false><<<N_TILES, 256, 0, stream>>>(
        mn, hB, Wl2, bl2, Wr2, hA, h8A, flags, d_out);
    gather_mean<true><<<2048, 256, 0, stream>>>(h8A, csr_pk, row_st, deg, inv_deg, mn, 0, N_HALF);
    gather_mean<true><<<2048, 256, 0, stream>>>(h8A, csr_pk, row_st, deg, inv_deg, mn, N_HALF, N_NODES);
    transform_mfma<H_DIM, true, false><<<N_TILES, 256, 0, stream>>>(
        mn, hA, Wl3, bl3, Wr3, hB, h8B, flags, d_out);
    gather_mean<false><<<2048, 256, 0, stream>>>(h8B, csr_pk, row_st, deg, inv_deg, mn, 0, N_HALF);
    gather_mean<false><<<2048, 256, 0, stream>>>(h8B, csr_pk, row_st, deg, inv_deg, mn, N_HALF, N_NODES);
    transform_mfma<C_NUM, false, true><<<N_TILES, 256, 0, stream>>>(
        mn, hB, Wl4, bl4, Wr4, nullptr, nullptr, flags, d_out);
}

// Round 13
// 536.048 us; speedup vs baseline: 1.0410x; 1.0410x over previous
//
#include <hip/hip_runtime.h>
#include <hip/hip_bf16.h>

#define N_NODES   100000
#define N_EDGES   3200000
#define F_IN      100
#define H_DIM     64
#define C_NUM     18
#define NPB       128                       // nodes per csr bucket
#define N_BKT     782                       // ceil(100000/128)
#define EPB_C     8192                      // edges per radix-count block
#define EPB_S     4096                      // edges per radix-scatter block
#define N_TILES   1563                      // ceil(100000/64)

typedef __attribute__((ext_vector_type(8))) short short8;
typedef __attribute__((ext_vector_type(4))) float f32x4;
typedef __attribute__((ext_vector_type(2))) float f32x2;

// ---- dtype-flexible loads (flags decided at runtime by detect_kernel) ----
__device__ __forceinline__ float ldf(const void* p, long long i, int isbf) {
    if (isbf) return __bfloat162float(((const __hip_bfloat16*)p)[i]);
    return ((const float*)p)[i];
}
// node indices are < 2^17, so for int64 input the LOW DWORD suffices
// (little-endian): halves edge-index traffic vs 8B loads.
__device__ __forceinline__ int ldi_lo(const void* p, long long i, int is64) {
    if (is64) return ((const int*)p)[2 * i];
    return ((const int*)p)[i];
}
__device__ __forceinline__ unsigned short f2us(float f) {
    __hip_bfloat16 b = __float2bfloat16(f);
    return *(unsigned short*)&b;
}
__device__ __forceinline__ unsigned char f2fp8(float f) {
    int p = __builtin_amdgcn_cvt_pk_fp8_f32(f, 0.0f, 0, false);
    return (unsigned char)(p & 0xFF);
}

// ---- probe input dtypes; write flags; zero pcnt (merged zero_cnt) ----
__global__ void detect_kernel(const void* ei, const void* x, int* flags,
                              int* __restrict__ pcnt)
{
    const int t = threadIdx.x;
    for (int i = t; i < N_BKT; i += 256) pcnt[i] = 0;
    if (t >= 64) return;
    const int lane = t;
    const long long* e64 = (const long long*)ei;
    int bad = 0;
#pragma unroll
    for (int i = lane; i < 128; i += 64) {
        long long v = e64[i];
        if (v < 0 || v >= N_NODES) bad = 1;
    }
    unsigned long long anybad = __ballot(bad);
    const __hip_bfloat16* xb = (const __hip_bfloat16*)x;
    int cnt = 0;
#pragma unroll
    for (int i = lane; i < 256; i += 64) {
        float v = fabsf(__bfloat162float(xb[i]));
        if (v == 0.0f || (v > 9.5367431640625e-7f && v < 1.0e6f)) ++cnt;
    }
#pragma unroll
    for (int m = 1; m <= 32; m <<= 1) cnt += __shfl_xor(cnt, m);
    if (lane == 0) {
        flags[0] = (anybad == 0ULL) ? 1 : 0;
        flags[1] = (cnt >= 240) ? 1 : 0;
    }
}

// ---- pass A: bucket histogram, LDS-privatized (bucket = dst>>7) ----
__global__ __launch_bounds__(1024) void radix_count(const void* ei, int* __restrict__ pcnt,
                                                    const int* __restrict__ flags)
{
    __shared__ int hist[N_BKT];
    const int t = threadIdx.x;
    if (t < N_BKT) hist[t] = 0;
    __syncthreads();
    const int base = blockIdx.x * EPB_C;
    const int n = min(EPB_C, N_EDGES - base);
    const int is64 = flags[0];
    for (int j = t; j < n; j += 1024) {
        int d = ldi_lo(ei, (long long)N_EDGES + base + j, is64);
        atomicAdd(&hist[d >> 7], 1);
    }
    __syncthreads();
    if (t < N_BKT) atomicAdd(&pcnt[t], hist[t]);
}

// ---- prefix scan over 782 bucket counts (single block of 1024) ----
__global__ __launch_bounds__(1024) void scan_bkt(const int* __restrict__ cnt,
                                                 int* __restrict__ base,
                                                 int* __restrict__ cursor)
{
    __shared__ int tmp[1024];
    const int t = threadIdx.x;
    int v = (t < N_BKT) ? cnt[t] : 0;
    tmp[t] = v;
    __syncthreads();
    for (int off = 1; off < 1024; off <<= 1) {
        int add = (t >= off) ? tmp[t - off] : 0;
        __syncthreads();
        tmp[t] += add;
        __syncthreads();
    }
    if (t < N_BKT) { base[t] = tmp[t] - v; cursor[t] = tmp[t] - v; }
    if (t == 1023) base[N_BKT] = tmp[1023];   // == N_EDGES
}

// ---- pass B: LDS-staged radix partition into contiguous bucket regions ----
// stage[].x: src:17b | local-node(7b)<<17 ; stage[].y: w16 | bucket<<16
__global__ __launch_bounds__(1024) void radix_scatter(const void* ei, const void* ew,
                                                      int* __restrict__ gcursor,
                                                      uint2* __restrict__ temp,
                                                      const int* __restrict__ flags)
{
    __shared__ uint2 stage[EPB_S];                // 32 KB
    __shared__ int hist[1024], scan_s[1024];      // 8 KB
    __shared__ int gbase[N_BKT], lcur[N_BKT];     // ~6.3 KB
    const int t = threadIdx.x;
    hist[t] = 0;
    __syncthreads();

    const int base = blockIdx.x * EPB_S;
    const int n = min(EPB_S, N_EDGES - base);
    const int is64 = flags[0], isbf = flags[1];

    int  bkt[4];
    uint2 pk[4];
#pragma unroll
    for (int j = 0; j < 4; ++j) {
        int i = j * 1024 + t;
        bkt[j] = -1;
        if (i < n) {
            int e = base + i;
            int s = ldi_lo(ei, e, is64);
            int d = ldi_lo(ei, (long long)N_EDGES + e, is64);
            float w = ldf(ew, e, isbf);
            bkt[j] = d >> 7;
            pk[j].x = (unsigned)s | ((unsigned)(d & (NPB - 1)) << 17);
            pk[j].y = (unsigned)f2us(w) | ((unsigned)bkt[j] << 16);
            atomicAdd(&hist[bkt[j]], 1);
        }
    }
    __syncthreads();
    scan_s[t] = hist[t];
    __syncthreads();
    for (int off = 1; off < 1024; off <<= 1) {
        int add = (t >= off) ? scan_s[t - off] : 0;
        __syncthreads();
        scan_s[t] += add;
        __syncthreads();
    }
    if (t < N_BKT) {
        int excl = scan_s[t] - hist[t];
        lcur[t] = excl;
        gbase[t] = atomicAdd(&gcursor[t], hist[t]) - excl;
    }
    __syncthreads();
#pragma unroll
    for (int j = 0; j < 4; ++j) {
        if (bkt[j] >= 0) {
            int pos = atomicAdd(&lcur[bkt[j]], 1);
            stage[pos] = pk[j];
        }
    }
    __syncthreads();
#pragma unroll
    for (int j = 0; j < 4; ++j) {
        int i = j * 1024 + t;
        if (i < n) {
            int b = (int)(stage[i].y >> 16);
            temp[gbase[b] + i] = stage[i];
        }
    }
}

// ---- pass C: per-bucket CSR finalize (128 nodes/block, 782 blocks) ----
// csr entry: src:17b | bf16-weight-without-sign:15b (weights >= 0)
__global__ __launch_bounds__(NPB) void csr_build(const uint2* __restrict__ temp,
                          const int* __restrict__ pbase,
                          unsigned int* __restrict__ csr_pk,
                          int* __restrict__ deg, int* __restrict__ row_start,
                          float* __restrict__ inv_deg)
{
    __shared__ int cnt[NPB], scan_s[NPB], cur[NPB];
    const int b = blockIdx.x;
    const int t = threadIdx.x;
    cnt[t] = 0;
    __syncthreads();
    const int bs = pbase[b];
    const int be = pbase[b + 1];
    for (int i = bs + t; i < be; i += NPB)
        atomicAdd(&cnt[(temp[i].x >> 17) & (NPB - 1)], 1);
    __syncthreads();
    int v = cnt[t];
    scan_s[t] = v;
    __syncthreads();
    for (int off = 1; off < NPB; off <<= 1) {
        int add = (t >= off) ? scan_s[t - off] : 0;
        __syncthreads();
        scan_s[t] += add;
        __syncthreads();
    }
    int excl = bs + scan_s[t] - v;
    cur[t] = excl;
    int node = b * NPB + t;
    if (node < N_NODES) {
        deg[node]       = v;
        row_start[node] = excl;
        inv_deg[node]   = 1.0f / (float)max(v, 1);
    }
    __syncthreads();
    for (int i = bs + t; i < be; i += NPB) {
        uint2 e = temp[i];
        int k = (e.x >> 17) & (NPB - 1);
        int pos = atomicAdd(&cur[k], 1);
        csr_pk[pos] = (e.x & 0x1FFFFu) | ((e.y & 0x7FFFu) << 17);
    }
}

// conflict-free W staging into W_s[n*KP + k] (KP=136): lane group n=t>>3, k8=t&7
template <int CP, int COUT>
__device__ __forceinline__ void stage_W(unsigned short* W_s, const void* Wl, const void* Wr,
                                        int t, int isbf)
{
    constexpr int KP = 136;
    const int n0 = t >> 3, k8a = t & 7;
    for (int n = n0; n < CP; n += 32) {
#pragma unroll
        for (int hh = 0; hh < 2; ++hh) {
            int k8 = k8a + hh * 8;
            union { unsigned short u[8]; short8 v; } tmp;
#pragma unroll
            for (int j = 0; j < 8; ++j) {
                int k = k8 * 8 + j;
                float val = 0.0f;
                if (n < COUT && k < 128)
                    val = (k < 64) ? ldf(Wl, (long long)k * COUT + n, isbf)
                                   : ldf(Wr, (long long)(k - 64) * COUT + n, isbf);
                tmp.u[j] = f2us(val);
            }
            *(short8*)&W_s[n * KP + k8 * 8] = tmp.v;
        }
    }
}

// ---- embedding via MFMA: h = relu(x @ W + b); also writes flat fp8 copy h8 ----
// NO x staging: each lane's A-fragment is 8 CONTIGUOUS bf16 of one x row
// (row = nb0+wave*16+c, cols kt*32+quad*8) -> two 8B direct global loads
// (row stride 200B => 8B-aligned; cols>=100 zero-filled via scalar path).
// One tile per block (grid=N_TILES), no per-tile barriers, LDS = W only
// (~18KB -> ~6 blocks/CU). r12 PMC showed the staged version at 47us with
// Occupancy 17% / VALU 11% / 616K LDS conflicts -- pure latency starvation.
__global__ __launch_bounds__(256) void embed_mfma(const void* x, const void* W, const void* b,
                           __hip_bfloat16* __restrict__ h,
                           unsigned char* __restrict__ h8,
                           const int* __restrict__ flags)
{
    constexpr int KP = 136;
    __shared__ unsigned short W_s[H_DIM * KP];
    __shared__ float b_s[H_DIM];
    const int t = threadIdx.x;
    const int isbf = flags[1];

    {
        const int n0 = t >> 3, k8a = t & 7;
        for (int n = n0; n < H_DIM; n += 32) {
#pragma unroll
            for (int hh = 0; hh < 2; ++hh) {
                int k8 = k8a + hh * 8;
                union { unsigned short u[8]; short8 v; } tmp;
#pragma unroll
                for (int j = 0; j < 8; ++j) {
                    int k = k8 * 8 + j;
                    tmp.u[j] = (k < F_IN) ? f2us(ldf(W, (long long)k * H_DIM + n, isbf))
                                          : (unsigned short)0;
                }
                *(short8*)&W_s[n * KP + k8 * 8] = tmp.v;
            }
        }
    }
    if (t < H_DIM) b_s[t] = ldf(b, t, isbf);
    __syncthreads();

    const int wave = t >> 6, lane = t & 63, c = lane & 15, quad = lane >> 4;
    const int nb0 = blockIdx.x * 64;

    // A-fragment row for this lane (clamped; garbage only affects the masked
    // output row nb0+wave*16+c itself, since MFMA A-row c -> C-row c).
    int arow = nb0 + wave * 16 + c;
    if (arow >= N_NODES) arow = N_NODES - 1;

    short8 afrag[4];
    if (isbf) {
        const unsigned short* xr = (const unsigned short*)x + (size_t)arow * F_IN;
#pragma unroll
        for (int kt = 0; kt < 4; ++kt) {
            union { unsigned short u[8]; short8 v; uint2 q[2]; } tmp;
            const int col0 = kt * 32 + quad * 8;
            if (col0 + 8 <= F_IN) {
                tmp.q[0] = *(const uint2*)(xr + col0);
                tmp.q[1] = *(const uint2*)(xr + col0 + 4);
            } else {
#pragma unroll
                for (int j = 0; j < 8; ++j) {
                    int cc = col0 + j;
                    tmp.u[j] = (cc < F_IN) ? xr[cc] : (unsigned short)0;
                }
            }
            afrag[kt] = tmp.v;
        }
    } else {
        const float* xr = (const float*)x + (size_t)arow * F_IN;
#pragma unroll
        for (int kt = 0; kt < 4; ++kt) {
            union { unsigned short u[8]; short8 v; } tmp;
            const int col0 = kt * 32 + quad * 8;
#pragma unroll
            for (int j = 0; j < 8; ++j) {
                int cc = col0 + j;
                tmp.u[j] = (cc < F_IN) ? f2us(xr[cc]) : (unsigned short)0;
            }
            afrag[kt] = tmp.v;
        }
    }

    short8 bfrag[4][4];
#pragma unroll
    for (int nt = 0; nt < 4; ++nt)
#pragma unroll
        for (int kt = 0; kt < 4; ++kt)
            bfrag[nt][kt] = *(const short8*)&W_s[(nt * 16 + c) * KP + kt * 32 + quad * 8];

    f32x4 acc[4] = {};
#pragma unroll
    for (int nt = 0; nt < 4; ++nt)
#pragma unroll
        for (int kt = 0; kt < 4; ++kt)
            acc[nt] = __builtin_amdgcn_mfma_f32_16x16x32_bf16(afrag[kt], bfrag[nt][kt], acc[nt], 0, 0, 0);

    const int nb = nb0 + wave * 16;
#pragma unroll
    for (int nt = 0; nt < 4; ++nt)
#pragma unroll
        for (int reg = 0; reg < 4; ++reg) {
            int nn = nb + quad * 4 + reg;
            int col = nt * 16 + c;
            if (nn < N_NODES) {
                float v = fmaxf(acc[nt][reg] + b_s[col], 0.0f);
                h[(size_t)nn * H_DIM + col] = __float2bfloat16(v);
                h8[(size_t)nn * H_DIM + col] = f2fp8(v);
            }
        }
}

// ---- gather: mean[n] = inv_deg * sum_j w_j * h8[src_j]; ONE node per wave ----
// Measured-best structure (r8/r11, ~51us): fp8 row = 64B = 4 lanes x dwordx4.
#define ACC16(HV, W) do {                                                          \
    f32x2 f_;                                                                      \
    f_ = __builtin_amdgcn_cvt_pk_f32_fp8((int)HV.x, false); a[0]=fmaf(W,f_.x,a[0]);  a[1]=fmaf(W,f_.y,a[1]);   \
    f_ = __builtin_amdgcn_cvt_pk_f32_fp8((int)HV.x, true ); a[2]=fmaf(W,f_.x,a[2]);  a[3]=fmaf(W,f_.y,a[3]);   \
    f_ = __builtin_amdgcn_cvt_pk_f32_fp8((int)HV.y, false); a[4]=fmaf(W,f_.x,a[4]);  a[5]=fmaf(W,f_.y,a[5]);   \
    f_ = __builtin_amdgcn_cvt_pk_f32_fp8((int)HV.y, true ); a[6]=fmaf(W,f_.x,a[6]);  a[7]=fmaf(W,f_.y,a[7]);   \
    f_ = __builtin_amdgcn_cvt_pk_f32_fp8((int)HV.z, false); a[8]=fmaf(W,f_.x,a[8]);  a[9]=fmaf(W,f_.y,a[9]);   \
    f_ = __builtin_amdgcn_cvt_pk_f32_fp8((int)HV.z, true ); a[10]=fmaf(W,f_.x,a[10]); a[11]=fmaf(W,f_.y,a[11]); \
    f_ = __builtin_amdgcn_cvt_pk_f32_fp8((int)HV.w, false); a[12]=fmaf(W,f_.x,a[12]); a[13]=fmaf(W,f_.y,a[13]); \
    f_ = __builtin_amdgcn_cvt_pk_f32_fp8((int)HV.w, true ); a[14]=fmaf(W,f_.x,a[14]); a[15]=fmaf(W,f_.y,a[15]); \
} while (0)

template <bool USE_W>
__global__ __launch_bounds__(256) void gather_mean(const unsigned char* __restrict__ h8,
                            const unsigned int* __restrict__ csr_pk,
                            const int* __restrict__ row_start,
                            const int* __restrict__ deg,
                            const float* __restrict__ inv_deg,
                            __hip_bfloat16* __restrict__ mean)
{
    const int lane = threadIdx.x & 63;
    const int c4 = lane & 3;
    const int r4 = lane >> 2;               // 0..15
    const int wid = blockIdx.x * 4 + (threadIdx.x >> 6);
    const int nw  = gridDim.x * 4;

    for (int n = wid; n < N_NODES; n += nw) {
        const int s0 = row_start[n];
        const int d0 = deg[n];
        unsigned int ev = (lane < d0) ? csr_pk[s0 + lane] : 0u;
        const int m0 = min(d0, 64);
        float a[16] = {};

        for (int j0 = 0; j0 < m0; j0 += 32) {   // wave-uniform: 1 or 2 iters
            unsigned int eA = __shfl(ev, j0 + r4);
            unsigned int eB = __shfl(ev, j0 + 16 + r4);
            uint4 hvA = *(const uint4*)(h8 + (size_t)(eA & 0x1FFFF) * H_DIM + 16 * c4);
            uint4 hvB = *(const uint4*)(h8 + (size_t)(eB & 0x1FFFF) * H_DIM + 16 * c4);
            float wA, wB;
            if (USE_W) {
                wA = __uint_as_float((eA & 0xFFFE0000u) >> 1);   // e=0 -> w=0
                wB = __uint_as_float((eB & 0xFFFE0000u) >> 1);
            } else {
                wA = (j0 + r4 < m0) ? 1.0f : 0.0f;
                wB = (j0 + 16 + r4 < m0) ? 1.0f : 0.0f;
            }
            ACC16(hvA, wA);
            ACC16(hvB, wB);
        }
        // rare tail (deg > 64)
        for (int jb = 64; jb < d0; jb += 16) {
            int j = jb + r4;
            unsigned int e2 = (j < d0) ? csr_pk[s0 + j] : 0u;
            float w;
            if (USE_W) w = __uint_as_float((e2 & 0xFFFE0000u) >> 1);
            else       w = (j < d0) ? 1.0f : 0.0f;
            uint4 hv = *(const uint4*)(h8 + (size_t)(e2 & 0x1FFFF) * H_DIM + 16 * c4);
            ACC16(hv, w);
        }

        // split-butterfly reduce over the 16 r4-groups (masks 4,8,16,32)
#pragma unroll
        for (int i = 0; i < 8; ++i) {
            float keep = (lane & 4) ? a[i + 8] : a[i];
            float give = (lane & 4) ? a[i] : a[i + 8];
            a[i] = keep + __shfl_xor(give, 4);
        }
#pragma unroll
        for (int i = 0; i < 4; ++i) {
            float keep = (lane & 8) ? a[i + 4] : a[i];
            float give = (lane & 8) ? a[i] : a[i + 4];
            a[i] = keep + __shfl_xor(give, 8);
        }
#pragma unroll
        for (int i = 0; i < 2; ++i) {
            float keep = (lane & 16) ? a[i + 2] : a[i];
            float give = (lane & 16) ? a[i] : a[i + 2];
            a[i] = keep + __shfl_xor(give, 16);
        }
        {
            float keep = (lane & 32) ? a[1] : a[0];
            float give = (lane & 32) ? a[0] : a[1];
            a[0] = keep + __shfl_xor(give, 32);
        }
        // lane's owned feature after the 4 keep-half decisions:
        const int f = c4 * 16 + ((lane >> 2) & 1) * 8 + ((lane >> 3) & 1) * 4
                    + ((lane >> 4) & 1) * 2 + ((lane >> 5) & 1);
        mean[(size_t)n * H_DIM + f] = __float2bfloat16(a[0] * inv_deg[n]);
    }
}

// ---- transform via MFMA: out = L2norm([mean|h] @ [Wl;Wr] + b) ----
// Non-final layers also write the flat fp8 copy for the next gather.
template <int COUT, bool RELU, bool FINAL>
__global__ void transform_mfma(const __hip_bfloat16* __restrict__ meanp,
                               const __hip_bfloat16* __restrict__ hp,
                               const void* Wl, const void* bl, const void* Wr,
                               __hip_bfloat16* __restrict__ h_out,
                               unsigned char* __restrict__ h8_out,
                               const int* __restrict__ flags, void* dout)
{
    constexpr int CP = (COUT + 15) & ~15;   // 64 or 32
    constexpr int NT = CP / 16;
    constexpr int KP = 136;
    __shared__ unsigned short W_s[CP * KP];
    __shared__ float b_s[CP];
    const int t = threadIdx.x;
    const int isbf = flags[1];
    stage_W<CP, COUT>(W_s, Wl, Wr, t, isbf);
    if (t < CP) b_s[t] = (t < COUT) ? ldf(bl, t, isbf) : 0.0f;
    __syncthreads();

    const int wave = t >> 6, lane = t & 63, c = lane & 15, quad = lane >> 4;
    short8 bfrag[NT][4];
#pragma unroll
    for (int nt = 0; nt < NT; ++nt)
#pragma unroll
        for (int kt = 0; kt < 4; ++kt)
            bfrag[nt][kt] = *(const short8*)&W_s[(nt * 16 + c) * KP + kt * 32 + quad * 8];

    for (int tile = blockIdx.x; tile < N_TILES; tile += gridDim.x) {
        const int nbw = tile * 64 + wave * 16;
        if (nbw >= N_NODES) continue;
        int node = nbw + c; if (node >= N_NODES) node = N_NODES - 1;

        short8 afrag[4];
#pragma unroll
        for (int kt = 0; kt < 4; ++kt) {
            const __hip_bfloat16* sp = (kt < 2) ? meanp : hp;
            afrag[kt] = *(const short8*)(sp + (size_t)node * H_DIM + (kt & 1) * 32 + quad * 8);
        }

        f32x4 acc[NT] = {};
#pragma unroll
        for (int nt = 0; nt < NT; ++nt)
#pragma unroll
            for (int kt = 0; kt < 4; ++kt)
                acc[nt] = __builtin_amdgcn_mfma_f32_16x16x32_bf16(afrag[kt], bfrag[nt][kt], acc[nt], 0, 0, 0);

        float rs[4];
#pragma unroll
        for (int reg = 0; reg < 4; ++reg) {
            float s2 = 0.f;
#pragma unroll
            for (int nt = 0; nt < NT; ++nt) {
                float v = acc[nt][reg] + b_s[nt * 16 + c];
                acc[nt][reg] = v;
                s2 += v * v;
            }
            s2 += __shfl_xor(s2, 1); s2 += __shfl_xor(s2, 2);
            s2 += __shfl_xor(s2, 4); s2 += __shfl_xor(s2, 8);
            rs[reg] = 1.0f / fmaxf(sqrtf(s2), 1e-12f);
        }

#pragma unroll
        for (int nt = 0; nt < NT; ++nt)
#pragma unroll
            for (int reg = 0; reg < 4; ++reg) {
                int nn  = nbw + quad * 4 + reg;
                int col = nt * 16 + c;
                if (nn < N_NODES && col < COUT) {
                    float v = acc[nt][reg] * rs[reg];
                    if (RELU) v = fmaxf(v, 0.0f);
                    if (FINAL) {
                        if (isbf) ((__hip_bfloat16*)dout)[(size_t)nn * COUT + col] = __float2bfloat16(v);
                        else      ((float*)dout)[(size_t)nn * COUT + col] = v;
                    } else {
                        h_out[(size_t)nn * H_DIM + col] = __float2bfloat16(v);
                        h8_out[(size_t)nn * H_DIM + col] = f2fp8(v);
                    }
                }
            }
    }
}

extern "C" void kernel_launch(void* const* d_in, const int* in_sizes, int n_in,
                              void* d_out, int out_size, void* d_ws, size_t ws_size,
                              hipStream_t stream)
{
    const void* x    = d_in[0];
    const void* ei   = d_in[1];
    const void* ew   = d_in[2];
    const void* embW = d_in[3];
    const void* embB = d_in[4];
    const void* Wl1 = d_in[5];  const void* bl1 = d_in[6];  const void* Wr1 = d_in[7];
    const void* Wl2 = d_in[8];  const void* bl2 = d_in[9];  const void* Wr2 = d_in[10];
    const void* Wl3 = d_in[11]; const void* bl3 = d_in[12]; const void* Wr3 = d_in[13];
    const void* Wl4 = d_in[14]; const void* bl4 = d_in[15]; const void* Wr4 = d_in[16];
    (void)in_sizes; (void)n_in; (void)out_size; (void)ws_size;

    char* ws = (char*)d_ws;
    size_t off = 0;
    auto alloc = [&](size_t bytes) -> void* {
        void* p = ws + off;
        off += (bytes + 255) & ~(size_t)255;
        return p;
    };
    // temp (edge staging, 25.6 MB) is dead after csr_build; hA/hB alias it.
    uint2* temp = (uint2*)alloc((size_t)N_EDGES * sizeof(uint2));
    __hip_bfloat16* hA = (__hip_bfloat16*)temp;
    __hip_bfloat16* hB = (__hip_bfloat16*)((char*)temp + (size_t)N_NODES * H_DIM * 2);
    unsigned int* csr_pk = (unsigned int*)alloc((size_t)N_EDGES * sizeof(unsigned int));
    __hip_bfloat16* mn = (__hip_bfloat16*)alloc((size_t)N_NODES * H_DIM * 2);  // 12.8 MB
    unsigned char* h8A = (unsigned char*)alloc((size_t)N_NODES * H_DIM);   // 6.4 MB
    unsigned char* h8B = (unsigned char*)alloc((size_t)N_NODES * H_DIM);   // 6.4 MB
    int*   pcnt    = (int*)  alloc((N_BKT)     * sizeof(int));
    int*   pbase   = (int*)  alloc((N_BKT + 1) * sizeof(int));
    int*   pcursor = (int*)  alloc((N_BKT)     * sizeof(int));
    int*   deg     = (int*)  alloc((size_t)N_NODES * sizeof(int));
    int*   row_st  = (int*)  alloc((size_t)N_NODES * sizeof(int));
    float* inv_deg = (float*)alloc((size_t)N_NODES * sizeof(float));
    int*   flags   = (int*)  alloc(256);

    const int NBc = (N_EDGES + EPB_C - 1) / EPB_C;   // 391 count blocks
    const int NBs = (N_EDGES + EPB_S - 1) / EPB_S;   // 782 scatter blocks

    detect_kernel<<<1, 256, 0, stream>>>(ei, x, flags, pcnt);
    radix_count<<<NBc, 1024, 0, stream>>>(ei, pcnt, flags);
    scan_bkt<<<1, 1024, 0, stream>>>(pcnt, pbase, pcursor);
    radix_scatter<<<NBs, 1024, 0, stream>>>(ei, ew, pcursor, temp, flags);
    csr_build<<<N_BKT, NPB, 0, stream>>>(temp, pbase, csr_pk, deg, row_st, inv_deg);

    embed_mfma<<<N_TILES, 256, 0, stream>>>(x, embW, embB, hA, h8A, flags);

    gather_mean<true><<<2048, 256, 0, stream>>>(h8A, csr_pk, row_st, deg, inv_deg, mn);
    transform_mfma<H_DIM, true, false><<<N_TILES, 256, 0, stream>>>(
        mn, hA, Wl1, bl1, Wr1, hB, h8B, flags, d_out);
    gather_mean<true><<<2048, 256, 0, stream>>>(h8B, csr_pk, row_st, deg, inv_deg, mn);
    transform_mfma<H_DIM, true, false><<<N_TILES, 256, 0, stream>>>(
        mn, hB, Wl2, bl2, Wr2, hA, h8A, flags, d_out);
    gather_mean<true><<<2048, 256, 0, stream>>>(h8A, csr_pk, row_st, deg, inv_deg, mn);
    transform_mfma<H_DIM, true, false><<<N_TILES, 256, 0, stream>>>(
        mn, hA, Wl3, bl3, Wr3, hB, h8B, flags, d_out);
    gather_mean<false><<<2048, 256, 0, stream>>>(h8B, csr_pk, row_st, deg, inv_deg, mn);
    transform_mfma<C_NUM, false, true><<<N_TILES, 256, 0, stream>>>(
        mn, hB, Wl4, bl4, Wr4, nullptr, nullptr, flags, d_out);
}

// Round 14
// 497.679 us; speedup vs baseline: 1.1212x; 1.0771x over previous
//
#include <hip/hip_runtime.h>
#include <hip/hip_bf16.h>

#define N_NODES   100000
#define N_EDGES   3200000
#define F_IN      100
#define H_DIM     64
#define C_NUM     18
#define NPB       128                       // nodes per csr bucket
#define N_BKT     782                       // ceil(100000/128)
#define EPB_C     8192                      // edges per radix-count block
#define EPB_S     4096                      // edges per radix-scatter block
#define N_TILES   1563                      // ceil(100000/64)
#define WSLOT     8192                      // 64*128 ushort per weight slot

typedef __attribute__((ext_vector_type(8))) short short8;
typedef __attribute__((ext_vector_type(4))) float f32x4;
typedef __attribute__((ext_vector_type(2))) float f32x2;

// ---- dtype-flexible loads (flags decided at runtime by detect_kernel) ----
__device__ __forceinline__ float ldf(const void* p, long long i, int isbf) {
    if (isbf) return __bfloat162float(((const __hip_bfloat16*)p)[i]);
    return ((const float*)p)[i];
}
// node indices are < 2^17, so for int64 input the LOW DWORD suffices
__device__ __forceinline__ int ldi_lo(const void* p, long long i, int is64) {
    if (is64) return ((const int*)p)[2 * i];
    return ((const int*)p)[i];
}
__device__ __forceinline__ unsigned short f2us(float f) {
    __hip_bfloat16 b = __float2bfloat16(f);
    return *(unsigned short*)&b;
}
__device__ __forceinline__ unsigned char f2fp8(float f) {
    int p = __builtin_amdgcn_cvt_pk_fp8_f32(f, 0.0f, 0, false);
    return (unsigned char)(p & 0xFF);
}

// ---- probe input dtypes; write flags; zero pcnt ----
__global__ void detect_kernel(const void* ei, const void* x, int* flags,
                              int* __restrict__ pcnt)
{
    const int t = threadIdx.x;
    for (int i = t; i < N_BKT; i += 256) pcnt[i] = 0;
    if (t >= 64) return;
    const int lane = t;
    const long long* e64 = (const long long*)ei;
    int bad = 0;
#pragma unroll
    for (int i = lane; i < 128; i += 64) {
        long long v = e64[i];
        if (v < 0 || v >= N_NODES) bad = 1;
    }
    unsigned long long anybad = __ballot(bad);
    const __hip_bfloat16* xb = (const __hip_bfloat16*)x;
    int cnt = 0;
#pragma unroll
    for (int i = lane; i < 256; i += 64) {
        float v = fabsf(__bfloat162float(xb[i]));
        if (v == 0.0f || (v > 9.5367431640625e-7f && v < 1.0e6f)) ++cnt;
    }
#pragma unroll
    for (int m = 1; m <= 32; m <<= 1) cnt += __shfl_xor(cnt, m);
    if (lane == 0) {
        flags[0] = (anybad == 0ULL) ? 1 : 0;
        flags[1] = (cnt >= 240) ? 1 : 0;
    }
}

// ---- one-shot weight transposition into fragment-ready layout ----
// Wt[slot][n][k] (k fast, stride 128): slot 0 = emb (k<100 from embW[k][n]),
// slots 1-3 = layers ([Wl;Wr] stacked on k), slot 4 = final (cout=18, padded).
// Bt[slot*64+n] = f32 bias. Runs ONCE -- removes the per-block stage_W
// preamble (≈256 strided scalar loads + LDS + barrier) that r12's PMC showed
// dominating embed (47us, 17% occupancy, nothing busy) and each transform.
__global__ __launch_bounds__(256) void prep_weights(
        const void* embW, const void* embB,
        const void* Wl1, const void* bl1, const void* Wr1,
        const void* Wl2, const void* bl2, const void* Wr2,
        const void* Wl3, const void* bl3, const void* Wr3,
        const void* Wl4, const void* bl4, const void* Wr4,
        unsigned short* __restrict__ Wt, float* __restrict__ Bt,
        const int* __restrict__ flags)
{
    const int s = blockIdx.x;          // 0..4
    const int t = threadIdx.x;
    const int isbf = flags[1];
    const void *Wl, *Wr, *bb; int cout;
    if      (s == 0) { Wl = embW; Wr = nullptr; bb = embB; cout = H_DIM; }
    else if (s == 1) { Wl = Wl1;  Wr = Wr1;  bb = bl1;  cout = H_DIM; }
    else if (s == 2) { Wl = Wl2;  Wr = Wr2;  bb = bl2;  cout = H_DIM; }
    else if (s == 3) { Wl = Wl3;  Wr = Wr3;  bb = bl3;  cout = H_DIM; }
    else             { Wl = Wl4;  Wr = Wr4;  bb = bl4;  cout = C_NUM; }

    unsigned short* w = Wt + (size_t)s * WSLOT;
    for (int i = t; i < 64 * 128; i += 256) {
        const int n = i >> 7, k = i & 127;
        float v = 0.0f;
        if (s == 0) {
            if (k < F_IN) v = ldf(Wl, (long long)k * H_DIM + n, isbf);
        } else if (n < cout) {
            v = (k < 64) ? ldf(Wl, (long long)k * cout + n, isbf)
                         : ldf(Wr, (long long)(k - 64) * cout + n, isbf);
        }
        w[i] = f2us(v);
    }
    if (t < 64) Bt[s * 64 + t] = (t < cout) ? ldf(bb, t, isbf) : 0.0f;
}

// ---- pass A: bucket histogram, LDS-privatized (bucket = dst>>7) ----
__global__ __launch_bounds__(1024) void radix_count(const void* ei, int* __restrict__ pcnt,
                                                    const int* __restrict__ flags)
{
    __shared__ int hist[N_BKT];
    const int t = threadIdx.x;
    if (t < N_BKT) hist[t] = 0;
    __syncthreads();
    const int base = blockIdx.x * EPB_C;
    const int n = min(EPB_C, N_EDGES - base);
    const int is64 = flags[0];
    for (int j = t; j < n; j += 1024) {
        int d = ldi_lo(ei, (long long)N_EDGES + base + j, is64);
        atomicAdd(&hist[d >> 7], 1);
    }
    __syncthreads();
    if (t < N_BKT) atomicAdd(&pcnt[t], hist[t]);
}

// ---- prefix scan over 782 bucket counts (single block of 1024) ----
__global__ __launch_bounds__(1024) void scan_bkt(const int* __restrict__ cnt,
                                                 int* __restrict__ base,
                                                 int* __restrict__ cursor)
{
    __shared__ int tmp[1024];
    const int t = threadIdx.x;
    int v = (t < N_BKT) ? cnt[t] : 0;
    tmp[t] = v;
    __syncthreads();
    for (int off = 1; off < 1024; off <<= 1) {
        int add = (t >= off) ? tmp[t - off] : 0;
        __syncthreads();
        tmp[t] += add;
        __syncthreads();
    }
    if (t < N_BKT) { base[t] = tmp[t] - v; cursor[t] = tmp[t] - v; }
    if (t == 1023) base[N_BKT] = tmp[1023];   // == N_EDGES
}

// ---- pass B: LDS-staged radix partition into contiguous bucket regions ----
__global__ __launch_bounds__(1024) void radix_scatter(const void* ei, const void* ew,
                                                      int* __restrict__ gcursor,
                                                      uint2* __restrict__ temp,
                                                      const int* __restrict__ flags)
{
    __shared__ uint2 stage[EPB_S];                // 32 KB
    __shared__ int hist[1024], scan_s[1024];      // 8 KB
    __shared__ int gbase[N_BKT], lcur[N_BKT];     // ~6.3 KB
    const int t = threadIdx.x;
    hist[t] = 0;
    __syncthreads();

    const int base = blockIdx.x * EPB_S;
    const int n = min(EPB_S, N_EDGES - base);
    const int is64 = flags[0], isbf = flags[1];

    int  bkt[4];
    uint2 pk[4];
#pragma unroll
    for (int j = 0; j < 4; ++j) {
        int i = j * 1024 + t;
        bkt[j] = -1;
        if (i < n) {
            int e = base + i;
            int s = ldi_lo(ei, e, is64);
            int d = ldi_lo(ei, (long long)N_EDGES + e, is64);
            float w = ldf(ew, e, isbf);
            bkt[j] = d >> 7;
            pk[j].x = (unsigned)s | ((unsigned)(d & (NPB - 1)) << 17);
            pk[j].y = (unsigned)f2us(w) | ((unsigned)bkt[j] << 16);
            atomicAdd(&hist[bkt[j]], 1);
        }
    }
    __syncthreads();
    scan_s[t] = hist[t];
    __syncthreads();
    for (int off = 1; off < 1024; off <<= 1) {
        int add = (t >= off) ? scan_s[t - off] : 0;
        __syncthreads();
        scan_s[t] += add;
        __syncthreads();
    }
    if (t < N_BKT) {
        int excl = scan_s[t] - hist[t];
        lcur[t] = excl;
        gbase[t] = atomicAdd(&gcursor[t], hist[t]) - excl;
    }
    __syncthreads();
#pragma unroll
    for (int j = 0; j < 4; ++j) {
        if (bkt[j] >= 0) {
            int pos = atomicAdd(&lcur[bkt[j]], 1);
            stage[pos] = pk[j];
        }
    }
    __syncthreads();
#pragma unroll
    for (int j = 0; j < 4; ++j) {
        int i = j * 1024 + t;
        if (i < n) {
            int b = (int)(stage[i].y >> 16);
            temp[gbase[b] + i] = stage[i];
        }
    }
}

// ---- pass C: per-bucket CSR finalize (128 nodes/block, 782 blocks) ----
__global__ __launch_bounds__(NPB) void csr_build(const uint2* __restrict__ temp,
                          const int* __restrict__ pbase,
                          unsigned int* __restrict__ csr_pk,
                          int* __restrict__ deg, int* __restrict__ row_start,
                          float* __restrict__ inv_deg)
{
    __shared__ int cnt[NPB], scan_s[NPB], cur[NPB];
    const int b = blockIdx.x;
    const int t = threadIdx.x;
    cnt[t] = 0;
    __syncthreads();
    const int bs = pbase[b];
    const int be = pbase[b + 1];
    for (int i = bs + t; i < be; i += NPB)
        atomicAdd(&cnt[(temp[i].x >> 17) & (NPB - 1)], 1);
    __syncthreads();
    int v = cnt[t];
    scan_s[t] = v;
    __syncthreads();
    for (int off = 1; off < NPB; off <<= 1) {
        int add = (t >= off) ? scan_s[t - off] : 0;
        __syncthreads();
        scan_s[t] += add;
        __syncthreads();
    }
    int excl = bs + scan_s[t] - v;
    cur[t] = excl;
    int node = b * NPB + t;
    if (node < N_NODES) {
        deg[node]       = v;
        row_start[node] = excl;
        inv_deg[node]   = 1.0f / (float)max(v, 1);
    }
    __syncthreads();
    for (int i = bs + t; i < be; i += NPB) {
        uint2 e = temp[i];
        int k = (e.x >> 17) & (NPB - 1);
        int pos = atomicAdd(&cur[k], 1);
        csr_pk[pos] = (e.x & 0x1FFFFu) | ((e.y & 0x7FFFu) << 17);
    }
}

// ---- embedding via MFMA: h = relu(x @ W + b); fp8 copy h8 ----
// NO LDS, no barriers: A-fragments direct from x (contiguous 8 bf16 per lane);
// B-fragments direct from pre-transposed Wt (16B coalesced, L2-hot).
__global__ __launch_bounds__(256) void embed_mfma(const void* x,
                           const unsigned short* __restrict__ Wt,
                           const float* __restrict__ Bt,
                           __hip_bfloat16* __restrict__ h,
                           unsigned char* __restrict__ h8,
                           const int* __restrict__ flags)
{
    const int t = threadIdx.x;
    const int isbf = flags[1];
    const int wave = t >> 6, lane = t & 63, c = lane & 15, quad = lane >> 4;
    const int nb0 = blockIdx.x * 64;

    int arow = nb0 + wave * 16 + c;
    if (arow >= N_NODES) arow = N_NODES - 1;

    short8 afrag[4];
    if (isbf) {
        const unsigned short* xr = (const unsigned short*)x + (size_t)arow * F_IN;
#pragma unroll
        for (int kt = 0; kt < 4; ++kt) {
            union { unsigned short u[8]; short8 v; uint2 q[2]; } tmp;
            const int col0 = kt * 32 + quad * 8;
            if (col0 + 8 <= F_IN) {
                tmp.q[0] = *(const uint2*)(xr + col0);
                tmp.q[1] = *(const uint2*)(xr + col0 + 4);
            } else {
#pragma unroll
                for (int j = 0; j < 8; ++j) {
                    int cc = col0 + j;
                    tmp.u[j] = (cc < F_IN) ? xr[cc] : (unsigned short)0;
                }
            }
            afrag[kt] = tmp.v;
        }
    } else {
        const float* xr = (const float*)x + (size_t)arow * F_IN;
#pragma unroll
        for (int kt = 0; kt < 4; ++kt) {
            union { unsigned short u[8]; short8 v; } tmp;
            const int col0 = kt * 32 + quad * 8;
#pragma unroll
            for (int j = 0; j < 8; ++j) {
                int cc = col0 + j;
                tmp.u[j] = (cc < F_IN) ? f2us(xr[cc]) : (unsigned short)0;
            }
            afrag[kt] = tmp.v;
        }
    }

    short8 bfrag[4][4];
#pragma unroll
    for (int nt = 0; nt < 4; ++nt)
#pragma unroll
        for (int kt = 0; kt < 4; ++kt)
            bfrag[nt][kt] = *(const short8*)&Wt[(nt * 16 + c) * 128 + kt * 32 + quad * 8];

    f32x4 acc[4] = {};
#pragma unroll
    for (int nt = 0; nt < 4; ++nt)
#pragma unroll
        for (int kt = 0; kt < 4; ++kt)
            acc[nt] = __builtin_amdgcn_mfma_f32_16x16x32_bf16(afrag[kt], bfrag[nt][kt], acc[nt], 0, 0, 0);

    const int nb = nb0 + wave * 16;
#pragma unroll
    for (int nt = 0; nt < 4; ++nt)
#pragma unroll
        for (int reg = 0; reg < 4; ++reg) {
            int nn = nb + quad * 4 + reg;
            int col = nt * 16 + c;
            if (nn < N_NODES) {
                float v = fmaxf(acc[nt][reg] + Bt[col], 0.0f);
                h[(size_t)nn * H_DIM + col] = __float2bfloat16(v);
                h8[(size_t)nn * H_DIM + col] = f2fp8(v);
            }
        }
}

// ---- gather: mean[n] = inv_deg * sum_j w_j * h8[src_j]; ONE node per wave ----
#define ACC16(HV, W) do {                                                          \
    f32x2 f_;                                                                      \
    f_ = __builtin_amdgcn_cvt_pk_f32_fp8((int)HV.x, false); a[0]=fmaf(W,f_.x,a[0]);  a[1]=fmaf(W,f_.y,a[1]);   \
    f_ = __builtin_amdgcn_cvt_pk_f32_fp8((int)HV.x, true ); a[2]=fmaf(W,f_.x,a[2]);  a[3]=fmaf(W,f_.y,a[3]);   \
    f_ = __builtin_amdgcn_cvt_pk_f32_fp8((int)HV.y, false); a[4]=fmaf(W,f_.x,a[4]);  a[5]=fmaf(W,f_.y,a[5]);   \
    f_ = __builtin_amdgcn_cvt_pk_f32_fp8((int)HV.y, true ); a[6]=fmaf(W,f_.x,a[6]);  a[7]=fmaf(W,f_.y,a[7]);   \
    f_ = __builtin_amdgcn_cvt_pk_f32_fp8((int)HV.z, false); a[8]=fmaf(W,f_.x,a[8]);  a[9]=fmaf(W,f_.y,a[9]);   \
    f_ = __builtin_amdgcn_cvt_pk_f32_fp8((int)HV.z, true ); a[10]=fmaf(W,f_.x,a[10]); a[11]=fmaf(W,f_.y,a[11]); \
    f_ = __builtin_amdgcn_cvt_pk_f32_fp8((int)HV.w, false); a[12]=fmaf(W,f_.x,a[12]); a[13]=fmaf(W,f_.y,a[13]); \
    f_ = __builtin_amdgcn_cvt_pk_f32_fp8((int)HV.w, true ); a[14]=fmaf(W,f_.x,a[14]); a[15]=fmaf(W,f_.y,a[15]); \
} while (0)

template <bool USE_W>
__global__ __launch_bounds__(256) void gather_mean(const unsigned char* __restrict__ h8,
                            const unsigned int* __restrict__ csr_pk,
                            const int* __restrict__ row_start,
                            const int* __restrict__ deg,
                            const float* __restrict__ inv_deg,
                            __hip_bfloat16* __restrict__ mean)
{
    const int lane = threadIdx.x & 63;
    const int c4 = lane & 3;
    const int r4 = lane >> 2;               // 0..15
    const int wid = blockIdx.x * 4 + (threadIdx.x >> 6);
    const int nw  = gridDim.x * 4;

    for (int n = wid; n < N_NODES; n += nw) {
        const int s0 = row_start[n];
        const int d0 = deg[n];
        unsigned int ev = (lane < d0) ? csr_pk[s0 + lane] : 0u;
        const int m0 = min(d0, 64);
        float a[16] = {};

        for (int j0 = 0; j0 < m0; j0 += 32) {   // wave-uniform: 1 or 2 iters
            unsigned int eA = __shfl(ev, j0 + r4);
            unsigned int eB = __shfl(ev, j0 + 16 + r4);
            uint4 hvA = *(const uint4*)(h8 + (size_t)(eA & 0x1FFFF) * H_DIM + 16 * c4);
            uint4 hvB = *(const uint4*)(h8 + (size_t)(eB & 0x1FFFF) * H_DIM + 16 * c4);
            float wA, wB;
            if (USE_W) {
                wA = __uint_as_float((eA & 0xFFFE0000u) >> 1);   // e=0 -> w=0
                wB = __uint_as_float((eB & 0xFFFE0000u) >> 1);
            } else {
                wA = (j0 + r4 < m0) ? 1.0f : 0.0f;
                wB = (j0 + 16 + r4 < m0) ? 1.0f : 0.0f;
            }
            ACC16(hvA, wA);
            ACC16(hvB, wB);
        }
        // rare tail (deg > 64)
        for (int jb = 64; jb < d0; jb += 16) {
            int j = jb + r4;
            unsigned int e2 = (j < d0) ? csr_pk[s0 + j] : 0u;
            float w;
            if (USE_W) w = __uint_as_float((e2 & 0xFFFE0000u) >> 1);
            else       w = (j < d0) ? 1.0f : 0.0f;
            uint4 hv = *(const uint4*)(h8 + (size_t)(e2 & 0x1FFFF) * H_DIM + 16 * c4);
            ACC16(hv, w);
        }

        // split-butterfly reduce over the 16 r4-groups (masks 4,8,16,32)
#pragma unroll
        for (int i = 0; i < 8; ++i) {
            float keep = (lane & 4) ? a[i + 8] : a[i];
            float give = (lane & 4) ? a[i] : a[i + 8];
            a[i] = keep + __shfl_xor(give, 4);
        }
#pragma unroll
        for (int i = 0; i < 4; ++i) {
            float keep = (lane & 8) ? a[i + 4] : a[i];
            float give = (lane & 8) ? a[i] : a[i + 4];
            a[i] = keep + __shfl_xor(give, 8);
        }
#pragma unroll
        for (int i = 0; i < 2; ++i) {
            float keep = (lane & 16) ? a[i + 2] : a[i];
            float give = (lane & 16) ? a[i] : a[i + 2];
            a[i] = keep + __shfl_xor(give, 16);
        }
        {
            float keep = (lane & 32) ? a[1] : a[0];
            float give = (lane & 32) ? a[0] : a[1];
            a[0] = keep + __shfl_xor(give, 32);
        }
        // lane's owned feature after the 4 keep-half decisions:
        const int f = c4 * 16 + ((lane >> 2) & 1) * 8 + ((lane >> 3) & 1) * 4
                    + ((lane >> 4) & 1) * 2 + ((lane >> 5) & 1);
        mean[(size_t)n * H_DIM + f] = __float2bfloat16(a[0] * inv_deg[n]);
    }
}

// ---- transform via MFMA: out = L2norm([mean|h] @ [Wl;Wr] + b) ----
// NO LDS, no barriers, no stage_W: B-fragments direct from pre-transposed Wt
// (16B coalesced, L2-hot, shared by all 1563 blocks). One tile per block.
template <int COUT, bool RELU, bool FINAL>
__global__ __launch_bounds__(256) void transform_mfma(
                               const __hip_bfloat16* __restrict__ meanp,
                               const __hip_bfloat16* __restrict__ hp,
                               const unsigned short* __restrict__ Wt,
                               const float* __restrict__ Bt,
                               __hip_bfloat16* __restrict__ h_out,
                               unsigned char* __restrict__ h8_out,
                               const int* __restrict__ flags, void* dout)
{
    constexpr int CP = (COUT + 15) & ~15;   // 64 or 32
    constexpr int NT = CP / 16;
    const int t = threadIdx.x;
    const int isbf = flags[1];
    const int wave = t >> 6, lane = t & 63, c = lane & 15, quad = lane >> 4;

    const int nbw = blockIdx.x * 64 + wave * 16;
    if (nbw >= N_NODES) return;
    int node = nbw + c; if (node >= N_NODES) node = N_NODES - 1;

    short8 bfrag[NT][4];
#pragma unroll
    for (int nt = 0; nt < NT; ++nt)
#pragma unroll
        for (int kt = 0; kt < 4; ++kt)
            bfrag[nt][kt] = *(const short8*)&Wt[(nt * 16 + c) * 128 + kt * 32 + quad * 8];

    short8 afrag[4];
#pragma unroll
    for (int kt = 0; kt < 4; ++kt) {
        const __hip_bfloat16* sp = (kt < 2) ? meanp : hp;
        afrag[kt] = *(const short8*)(sp + (size_t)node * H_DIM + (kt & 1) * 32 + quad * 8);
    }

    f32x4 acc[NT] = {};
#pragma unroll
    for (int nt = 0; nt < NT; ++nt)
#pragma unroll
        for (int kt = 0; kt < 4; ++kt)
            acc[nt] = __builtin_amdgcn_mfma_f32_16x16x32_bf16(afrag[kt], bfrag[nt][kt], acc[nt], 0, 0, 0);

    float rs[4];
#pragma unroll
    for (int reg = 0; reg < 4; ++reg) {
        float s2 = 0.f;
#pragma unroll
        for (int nt = 0; nt < NT; ++nt) {
            float v = acc[nt][reg] + Bt[nt * 16 + c];
            acc[nt][reg] = v;
            s2 += v * v;
        }
        s2 += __shfl_xor(s2, 1); s2 += __shfl_xor(s2, 2);
        s2 += __shfl_xor(s2, 4); s2 += __shfl_xor(s2, 8);
        rs[reg] = 1.0f / fmaxf(sqrtf(s2), 1e-12f);
    }

#pragma unroll
    for (int nt = 0; nt < NT; ++nt)
#pragma unroll
        for (int reg = 0; reg < 4; ++reg) {
            int nn  = nbw + quad * 4 + reg;
            int col = nt * 16 + c;
            if (nn < N_NODES && col < COUT) {
                float v = acc[nt][reg] * rs[reg];
                if (RELU) v = fmaxf(v, 0.0f);
                if (FINAL) {
                    if (isbf) ((__hip_bfloat16*)dout)[(size_t)nn * COUT + col] = __float2bfloat16(v);
                    else      ((float*)dout)[(size_t)nn * COUT + col] = v;
                } else {
                    h_out[(size_t)nn * H_DIM + col] = __float2bfloat16(v);
                    h8_out[(size_t)nn * H_DIM + col] = f2fp8(v);
                }
            }
        }
}

extern "C" void kernel_launch(void* const* d_in, const int* in_sizes, int n_in,
                              void* d_out, int out_size, void* d_ws, size_t ws_size,
                              hipStream_t stream)
{
    const void* x    = d_in[0];
    const void* ei   = d_in[1];
    const void* ew   = d_in[2];
    const void* embW = d_in[3];
    const void* embB = d_in[4];
    const void* Wl1 = d_in[5];  const void* bl1 = d_in[6];  const void* Wr1 = d_in[7];
    const void* Wl2 = d_in[8];  const void* bl2 = d_in[9];  const void* Wr2 = d_in[10];
    const void* Wl3 = d_in[11]; const void* bl3 = d_in[12]; const void* Wr3 = d_in[13];
    const void* Wl4 = d_in[14]; const void* bl4 = d_in[15]; const void* Wr4 = d_in[16];
    (void)in_sizes; (void)n_in; (void)out_size; (void)ws_size;

    char* ws = (char*)d_ws;
    size_t off = 0;
    auto alloc = [&](size_t bytes) -> void* {
        void* p = ws + off;
        off += (bytes + 255) & ~(size_t)255;
        return p;
    };
    // temp (edge staging, 25.6 MB) is dead after csr_build; hA/hB alias it.
    uint2* temp = (uint2*)alloc((size_t)N_EDGES * sizeof(uint2));
    __hip_bfloat16* hA = (__hip_bfloat16*)temp;
    __hip_bfloat16* hB = (__hip_bfloat16*)((char*)temp + (size_t)N_NODES * H_DIM * 2);
    unsigned int* csr_pk = (unsigned int*)alloc((size_t)N_EDGES * sizeof(unsigned int));
    __hip_bfloat16* mn = (__hip_bfloat16*)alloc((size_t)N_NODES * H_DIM * 2);  // 12.8 MB
    unsigned char* h8A = (unsigned char*)alloc((size_t)N_NODES * H_DIM);   // 6.4 MB
    unsigned char* h8B = (unsigned char*)alloc((size_t)N_NODES * H_DIM);   // 6.4 MB
    unsigned short* Wt = (unsigned short*)alloc(5 * WSLOT * sizeof(unsigned short));
    float* Bt          = (float*)alloc(5 * 64 * sizeof(float));
    int*   pcnt    = (int*)  alloc((N_BKT)     * sizeof(int));
    int*   pbase   = (int*)  alloc((N_BKT + 1) * sizeof(int));
    int*   pcursor = (int*)  alloc((N_BKT)     * sizeof(int));
    int*   deg     = (int*)  alloc((size_t)N_NODES * sizeof(int));
    int*   row_st  = (int*)  alloc((size_t)N_NODES * sizeof(int));
    float* inv_deg = (float*)alloc((size_t)N_NODES * sizeof(float));
    int*   flags   = (int*)  alloc(256);

    const int NBc = (N_EDGES + EPB_C - 1) / EPB_C;   // 391 count blocks
    const int NBs = (N_EDGES + EPB_S - 1) / EPB_S;   // 782 scatter blocks

    detect_kernel<<<1, 256, 0, stream>>>(ei, x, flags, pcnt);
    prep_weights<<<5, 256, 0, stream>>>(embW, embB, Wl1, bl1, Wr1, Wl2, bl2, Wr2,
                                        Wl3, bl3, Wr3, Wl4, bl4, Wr4, Wt, Bt, flags);
    radix_count<<<NBc, 1024, 0, stream>>>(ei, pcnt, flags);
    scan_bkt<<<1, 1024, 0, stream>>>(pcnt, pbase, pcursor);
    radix_scatter<<<NBs, 1024, 0, stream>>>(ei, ew, pcursor, temp, flags);
    csr_build<<<N_BKT, NPB, 0, stream>>>(temp, pbase, csr_pk, deg, row_st, inv_deg);

    embed_mfma<<<N_TILES, 256, 0, stream>>>(x, Wt, Bt, hA, h8A, flags);

    gather_mean<true><<<2048, 256, 0, stream>>>(h8A, csr_pk, row_st, deg, inv_deg, mn);
    transform_mfma<H_DIM, true, false><<<N_TILES, 256, 0, stream>>>(
        mn, hA, Wt + 1 * WSLOT, Bt + 64, hB, h8B, flags, d_out);
    gather_mean<true><<<2048, 256, 0, stream>>>(h8B, csr_pk, row_st, deg, inv_deg, mn);
    transform_mfma<H_DIM, true, false><<<N_TILES, 256, 0, stream>>>(
        mn, hB, Wt + 2 * WSLOT, Bt + 128, hA, h8A, flags, d_out);
    gather_mean<true><<<2048, 256, 0, stream>>>(h8A, csr_pk, row_st, deg, inv_deg, mn);
    transform_mfma<H_DIM, true, false><<<N_TILES, 256, 0, stream>>>(
        mn, hA, Wt + 3 * WSLOT, Bt + 192, hB, h8B, flags, d_out);
    gather_mean<false><<<2048, 256, 0, stream>>>(h8B, csr_pk, row_st, deg, inv_deg, mn);
    transform_mfma<C_NUM, false, true><<<N_TILES, 256, 0, stream>>>(
        mn, hB, Wt + 4 * WSLOT, Bt + 256, nullptr, nullptr, flags, d_out);
}